// Round 2
// baseline (1080.359 us; speedup 1.0000x reference)
//
#include <hip/hip_runtime.h>
#include <stdint.h>

#define NIMG 16
#define HIN 512
#define WIN 512
#define HO 256
#define WO 256

typedef unsigned short bf16_t;
typedef unsigned int u32;

// ---------- bf16 helpers (storage only; all math in f32) ----------
static __device__ __forceinline__ bf16_t f2bf(float f) {
    u32 u = __float_as_uint(f);
    u += 0x7FFFu + ((u >> 16) & 1u);   // RNE
    return (bf16_t)(u >> 16);
}
static __device__ __forceinline__ float bf_lo(u32 u) { return __uint_as_float(u << 16); }
static __device__ __forceinline__ float bf_hi(u32 u) { return __uint_as_float(u & 0xFFFF0000u); }
static __device__ __forceinline__ u32 pack2(float a, float b) {
    return (u32)f2bf(a) | ((u32)f2bf(b) << 16);
}

// ---------- repack dec_w [co][ci][3][3] -> wT [ci][r][co] ----------
__global__ void repack_decw(const float* __restrict__ dec_w, float* __restrict__ wT) {
    int i = blockIdx.x * 256 + threadIdx.x;   // 64*64*9 = 36864
    if (i >= 64 * 64 * 9) return;
    int co  = i / 576;
    int rem = i - co * 576;
    int ci  = rem / 9;
    int r   = rem - ci * 9;
    wT[(ci * 9 + r) * 64 + co] = dec_w[i];
}

// ---------- encoder: x[b][3][512][512] -> f[z][g4][256][256][16] bf16 ----------
__global__ __launch_bounds__(256) void encoder_kernel(
    const float* __restrict__ x, const float* __restrict__ enc_w,
    const float* __restrict__ enc_b, bf16_t* __restrict__ f, int b0)
{
    __shared__ __align__(16) float ew[27][64];   // [ci*9+r][co]
    __shared__ float eb[64];
    const int tid = threadIdx.x;
    for (int i = tid; i < 27 * 64; i += 256) {
        int co = i & 63, q = i >> 6;
        ew[q][co] = enc_w[co * 27 + q];
    }
    if (tid < 64) eb[tid] = enc_b[tid];
    __syncthreads();

    const int z  = blockIdx.z;
    const int b  = b0 + z;
    const int oy = (blockIdx.y << 4) + (tid >> 4);
    const int ox = (blockIdx.x << 4) + (tid & 15);
    const int ix0 = ox * 2;

    float acc[64];
    #pragma unroll
    for (int c = 0; c < 64; ++c) acc[c] = eb[c];

    const float* xb = x + (size_t)b * 3 * HIN * WIN;
    #pragma unroll 1
    for (int ci = 0; ci < 3; ++ci) {
        #pragma unroll 1
        for (int dy = 0; dy < 3; ++dy) {
            const int iy = oy * 2 + dy;           // SAME stride2: pad_lo = 0, pad_hi = 1
            float v0 = 0.f, v1 = 0.f, v2 = 0.f;
            if (iy < HIN) {
                const float* row = xb + (size_t)ci * HIN * WIN + (size_t)iy * WIN + ix0;
                float2 p = *(const float2*)row;    // ix0 <= 510, so ix0..ix0+1 always valid
                v0 = p.x; v1 = p.y;
                v2 = (ix0 + 2 < WIN) ? row[2] : 0.f;
            }
            const float vv[3] = {v0, v1, v2};
            #pragma unroll
            for (int dx = 0; dx < 3; ++dx) {
                const float v = vv[dx];
                const float* wr = &ew[ci * 9 + dy * 3 + dx][0];
                #pragma unroll
                for (int q = 0; q < 16; ++q) {
                    float4 wq = *(const float4*)(wr + q * 4);
                    acc[q*4+0] = fmaf(v, wq.x, acc[q*4+0]);
                    acc[q*4+1] = fmaf(v, wq.y, acc[q*4+1]);
                    acc[q*4+2] = fmaf(v, wq.z, acc[q*4+2]);
                    acc[q*4+3] = fmaf(v, wq.w, acc[q*4+3]);
                }
            }
        }
    }
    const size_t pix = (size_t)oy * WO + ox;
    #pragma unroll
    for (int g = 0; g < 4; ++g) {
        float r[16];
        #pragma unroll
        for (int k = 0; k < 16; ++k) {
            float t = acc[g * 16 + k];
            r[k] = t > 0.f ? t : 0.f;
        }
        u32* dst = (u32*)(f + ((size_t)(z * 4 + g) * (HO * WO) + pix) * 16);
        ((uint4*)dst)[0] = make_uint4(pack2(r[0],r[1]),  pack2(r[2],r[3]),
                                      pack2(r[4],r[5]),  pack2(r[6],r[7]));
        ((uint4*)dst)[1] = make_uint4(pack2(r[8],r[9]),  pack2(r[10],r[11]),
                                      pack2(r[12],r[13]),pack2(r[14],r[15]));
    }
}

// ---------- decoder: f -> d, 3x3 conv 64->64 + bias + relu ----------
__global__ __launch_bounds__(256) void decoder_kernel(
    const bf16_t* __restrict__ f, const float* __restrict__ wT,
    const float* __restrict__ dec_b, bf16_t* __restrict__ d)
{
    __shared__ __align__(16) float lds_f[16][18][20];   // [ci][y][x], x padded to 20
    __shared__ __align__(16) float lds_w[144][64];      // [(ci*9+r)][co]

    const int tid = threadIdx.x;
    const int wv = tid >> 6;          // co group
    const int lane = tid & 63;
    const int lx = lane & 7, ly = lane >> 3;
    const int z  = blockIdx.z;
    const int y0 = blockIdx.y << 4, x0 = blockIdx.x << 4;

    float acc[2][2][16];
    #pragma unroll
    for (int py = 0; py < 2; ++py)
        #pragma unroll
        for (int px = 0; px < 2; ++px)
            #pragma unroll
            for (int k = 0; k < 16; ++k) acc[py][px][k] = 0.f;

    #pragma unroll 1
    for (int g = 0; g < 4; ++g) {
        __syncthreads();
        // weights: contiguous 9216 f32 chunk
        {
            const float4* src = (const float4*)(wT + (size_t)g * 9216);
            float4* dst = (float4*)&lds_w[0][0];
            for (int i = tid; i < 2304; i += 256) dst[i] = src[i];
        }
        // f tile 18x18 x 16ci, zero-padded at image border
        const bf16_t* fplane = f + (size_t)(z * 4 + g) * (HO * WO) * 16;
        for (int i = tid; i < 648; i += 256) {
            const int pix = i >> 1, half = i & 1;
            const int yy = pix / 18, xx = pix - yy * 18;
            const int gy = y0 + yy - 1, gx = x0 + xx - 1;
            uint4 val = make_uint4(0u, 0u, 0u, 0u);
            if (gy >= 0 && gy < HO && gx >= 0 && gx < WO)
                val = *(const uint4*)(fplane + ((size_t)gy * WO + gx) * 16 + half * 8);
            const int cb = half * 8;
            lds_f[cb+0][yy][xx] = bf_lo(val.x);
            lds_f[cb+1][yy][xx] = bf_hi(val.x);
            lds_f[cb+2][yy][xx] = bf_lo(val.y);
            lds_f[cb+3][yy][xx] = bf_hi(val.y);
            lds_f[cb+4][yy][xx] = bf_lo(val.z);
            lds_f[cb+5][yy][xx] = bf_hi(val.z);
            lds_f[cb+6][yy][xx] = bf_lo(val.w);
            lds_f[cb+7][yy][xx] = bf_hi(val.w);
        }
        __syncthreads();

        #pragma unroll 1
        for (int ci = 0; ci < 16; ++ci) {
            float in[4][4];
            #pragma unroll
            for (int yy = 0; yy < 4; ++yy) {
                float2 p0 = *(const float2*)&lds_f[ci][2*ly + yy][2*lx];
                float2 p1 = *(const float2*)&lds_f[ci][2*ly + yy][2*lx + 2];
                in[yy][0] = p0.x; in[yy][1] = p0.y; in[yy][2] = p1.x; in[yy][3] = p1.y;
            }
            const float* wb = &lds_w[ci * 9][0] + wv * 16;
            #pragma unroll
            for (int dy = 0; dy < 3; ++dy) {
                #pragma unroll
                for (int dx = 0; dx < 3; ++dx) {
                    const float* wr = wb + (dy * 3 + dx) * 64;
                    #pragma unroll
                    for (int q = 0; q < 4; ++q) {
                        float4 wq = *(const float4*)(wr + q * 4);
                        #pragma unroll
                        for (int py = 0; py < 2; ++py)
                            #pragma unroll
                            for (int px = 0; px < 2; ++px) {
                                const float iv = in[py + dy][px + dx];
                                acc[py][px][q*4+0] = fmaf(iv, wq.x, acc[py][px][q*4+0]);
                                acc[py][px][q*4+1] = fmaf(iv, wq.y, acc[py][px][q*4+1]);
                                acc[py][px][q*4+2] = fmaf(iv, wq.z, acc[py][px][q*4+2]);
                                acc[py][px][q*4+3] = fmaf(iv, wq.w, acc[py][px][q*4+3]);
                            }
                    }
                }
            }
        }
    }

    float bias[16];
    #pragma unroll
    for (int k = 0; k < 16; ++k) bias[k] = dec_b[wv * 16 + k];
    bf16_t* dplane = d + (size_t)(z * 4 + wv) * (HO * WO) * 16;
    #pragma unroll
    for (int py = 0; py < 2; ++py)
        #pragma unroll
        for (int px = 0; px < 2; ++px) {
            float r[16];
            #pragma unroll
            for (int k = 0; k < 16; ++k) {
                float t = acc[py][px][k] + bias[k];
                r[k] = t > 0.f ? t : 0.f;
            }
            const size_t pix = (size_t)(y0 + 2*ly + py) * WO + (x0 + 2*lx + px);
            u32* dst = (u32*)(dplane + pix * 16);
            ((uint4*)dst)[0] = make_uint4(pack2(r[0],r[1]),  pack2(r[2],r[3]),
                                          pack2(r[4],r[5]),  pack2(r[6],r[7]));
            ((uint4*)dst)[1] = make_uint4(pack2(r[8],r[9]),  pack2(r[10],r[11]),
                                          pack2(r[12],r[13]),pack2(r[14],r[15]));
        }
}

// ---------- head: d -> out, per-sample routed 3x3 conv 64->1 + bias ----------
__global__ __launch_bounds__(256) void head_kernel(
    const bf16_t* __restrict__ d, const float* __restrict__ head_w,
    const float* __restrict__ head_b, const int* __restrict__ cls_id,
    float* __restrict__ out, int b0)
{
    __shared__ __align__(16) bf16_t lds_d[18][18][72];   // ci padded 64->72
    __shared__ __align__(16) float lds_hw[9][64];

    const int tid = threadIdx.x;
    const int z  = blockIdx.z;
    const int b  = b0 + z;
    const int y0 = blockIdx.y << 4, x0 = blockIdx.x << 4;
    const int cls = cls_id[b];

    for (int i = tid; i < 576; i += 256) {
        int r = i >> 6, ci = i & 63;
        lds_hw[r][ci] = head_w[((size_t)cls * 64 + ci) * 9 + r];
    }
    for (int i = tid; i < 2592; i += 256) {   // 324 px * 4 planes * 2 halves
        const int pix = i >> 3, q = i & 7;
        const int g = q >> 1, half = q & 1;
        const int yy = pix / 18, xx = pix - yy * 18;
        const int gy = y0 + yy - 1, gx = x0 + xx - 1;
        uint4 val = make_uint4(0u, 0u, 0u, 0u);
        if (gy >= 0 && gy < HO && gx >= 0 && gx < WO)
            val = *(const uint4*)(d + ((size_t)(z*4+g) * (HO*WO) + (size_t)gy * WO + gx) * 16 + half * 8);
        *(uint4*)&lds_d[yy][xx][g * 16 + half * 8] = val;
    }
    __syncthreads();

    const int py = tid >> 4, px = tid & 15;
    float acc = head_b[cls];
    #pragma unroll 1
    for (int dy = 0; dy < 3; ++dy) {
        #pragma unroll
        for (int dx = 0; dx < 3; ++dx) {
            const bf16_t* drow = &lds_d[py + dy][px + dx][0];
            const float* wr = &lds_hw[dy * 3 + dx][0];
            #pragma unroll
            for (int c8 = 0; c8 < 8; ++c8) {
                uint4 dv = *(const uint4*)(drow + c8 * 8);
                float4 w0 = *(const float4*)(wr + c8 * 8);
                float4 w1 = *(const float4*)(wr + c8 * 8 + 4);
                acc = fmaf(bf_lo(dv.x), w0.x, acc);
                acc = fmaf(bf_hi(dv.x), w0.y, acc);
                acc = fmaf(bf_lo(dv.y), w0.z, acc);
                acc = fmaf(bf_hi(dv.y), w0.w, acc);
                acc = fmaf(bf_lo(dv.z), w1.x, acc);
                acc = fmaf(bf_hi(dv.z), w1.y, acc);
                acc = fmaf(bf_lo(dv.w), w1.z, acc);
                acc = fmaf(bf_hi(dv.w), w1.w, acc);
            }
        }
    }
    out[(size_t)b * (HO * WO) + (size_t)(y0 + py) * WO + (x0 + px)] = acc;
}

extern "C" void kernel_launch(void* const* d_in, const int* in_sizes, int n_in,
                              void* d_out, int out_size, void* d_ws, size_t ws_size,
                              hipStream_t stream) {
    const float* x      = (const float*)d_in[0];
    const int*   cls_id = (const int*)  d_in[1];
    const float* enc_w  = (const float*)d_in[2];
    const float* enc_b  = (const float*)d_in[3];
    const float* dec_w  = (const float*)d_in[4];
    const float* dec_b  = (const float*)d_in[5];
    const float* head_w = (const float*)d_in[6];
    const float* head_b = (const float*)d_in[7];
    float* out = (float*)d_out;

    // Workspace layout (adaptive to ws_size):
    //   [0, 256KB)        : wT repacked decoder weights (147,456 B used)
    //   [256KB, ...)      : fbuf (C images) then dbuf (C images)
    // Per image per buffer: 4 groups * 256*256 px * 16 ch * 2 B = 8,388,608 B.
    const size_t WT_RESERVE = 262144;
    const size_t PER_IMG    = 8388608;
    char* ws = (char*)d_ws;
    float* wT = (float*)ws;

    size_t avail = (ws_size > WT_RESERVE) ? (ws_size - WT_RESERVE) : 0;
    int C = (int)(avail / (2 * PER_IMG));
    if (C < 1) C = 1;          // assume harness provides at least ~17 MB
    if (C > NIMG) C = NIMG;

    bf16_t* fbuf = (bf16_t*)(ws + WT_RESERVE);
    bf16_t* dbuf = (bf16_t*)(ws + WT_RESERVE + (size_t)C * PER_IMG);

    repack_decw<<<dim3(144), 256, 0, stream>>>(dec_w, wT);

    for (int b0 = 0; b0 < NIMG; b0 += C) {
        const int n = (NIMG - b0 < C) ? (NIMG - b0) : C;
        encoder_kernel<<<dim3(16, 16, n), 256, 0, stream>>>(x, enc_w, enc_b, fbuf, b0);
        decoder_kernel<<<dim3(16, 16, n), 256, 0, stream>>>(fbuf, wT, dec_b, dbuf);
        head_kernel   <<<dim3(16, 16, n), 256, 0, stream>>>(dbuf, head_w, head_b, cls_id, out, b0);
    }
}

// Round 4
// 679.357 us; speedup vs baseline: 1.5903x; 1.5903x over previous
//
#include <hip/hip_runtime.h>
#include <stdint.h>

#define NIMG 16
#define HIN 512
#define WIN 512
#define HO 256
#define WO 256
#define HP 258
#define WP 258

typedef unsigned short bf16_t;
typedef unsigned int u32;
typedef short bf16x8 __attribute__((ext_vector_type(8)));
typedef float f32x4 __attribute__((ext_vector_type(4)));

// ---------- bf16 helpers ----------
static __device__ __forceinline__ bf16_t f2bf(float f) {
    u32 u = __float_as_uint(f);
    u += 0x7FFFu + ((u >> 16) & 1u);   // RNE
    return (bf16_t)(u >> 16);
}
static __device__ __forceinline__ float bf_lo(u32 u) { return __uint_as_float(u << 16); }
static __device__ __forceinline__ float bf_hi(u32 u) { return __uint_as_float(u & 0xFFFF0000u); }
static __device__ __forceinline__ u32 pack2(float a, float b) {
    return (u32)f2bf(a) | ((u32)f2bf(b) << 16);
}

// ---------- repack dec_w [co][ci][3][3] f32 -> wB bf16 in MFMA B-fragment order ----------
// wB[((r*2+kc)*4+n)*64 + l][j] = w[co=4*(l&15)+n][ci=kc*32+(l>>4)*8+j][r]
__global__ void repack_decw(const float* __restrict__ dec_w, bf16_t* __restrict__ wB) {
    int i = blockIdx.x * 256 + threadIdx.x;   // 9*2*4*64*8 = 36864
    if (i >= 36864) return;
    int j  = i & 7;
    int l  = (i >> 3) & 63;
    int n  = (i >> 9) & 3;
    int kc = (i >> 11) & 1;
    int r  = i >> 12;
    int co = 4 * (l & 15) + n;
    int ci = kc * 32 + (l >> 4) * 8 + j;
    wB[i] = f2bf(dec_w[(co * 64 + ci) * 9 + r]);
}

// ---------- zero the 1-px halo of a padded NHWC [nimg][258][258][64] bf16 buffer ----------
__global__ void zero_halo(bf16_t* __restrict__ buf, int nimg) {
    const int per_img = 1028 * 8;   // border pixels * 8 chunks of 16B
    int i = blockIdx.x * 256 + threadIdx.x;
    if (i >= nimg * per_img) return;
    int z = i / per_img;
    int rem = i - z * per_img;
    int p = rem >> 3, q = rem & 7;
    int row, col;
    if (p < 258)      { row = 0;           col = p; }
    else if (p < 516) { row = 257;         col = p - 258; }
    else if (p < 772) { row = p - 516 + 1; col = 0; }
    else              { row = p - 772 + 1; col = 257; }
    *(uint4*)(buf + ((size_t)z * HP * WP + (size_t)row * WP + col) * 64 + q * 8) =
        make_uint4(0u, 0u, 0u, 0u);
}

// ---------- encoder: x[b][3][512][512] f32 -> f[z][258][258][64] bf16 (padded NHWC) ----------
__global__ __launch_bounds__(256) void encoder_kernel(
    const float* __restrict__ x, const float* __restrict__ enc_w,
    const float* __restrict__ enc_b, bf16_t* __restrict__ f, int b0)
{
    __shared__ __align__(16) float ew[27][64];
    __shared__ float eb[64];
    const int tid = threadIdx.x;
    for (int i = tid; i < 27 * 64; i += 256) {
        int co = i & 63, q = i >> 6;
        ew[q][co] = enc_w[co * 27 + q];
    }
    if (tid < 64) eb[tid] = enc_b[tid];
    __syncthreads();

    const int z  = blockIdx.z;
    const int b  = b0 + z;
    const int oy = (blockIdx.y << 4) + (tid >> 4);
    const int ox = (blockIdx.x << 4) + (tid & 15);
    const int ix0 = ox * 2;

    float acc[64];
    #pragma unroll
    for (int c = 0; c < 64; ++c) acc[c] = eb[c];

    const float* xb = x + (size_t)b * 3 * HIN * WIN;
    #pragma unroll 1
    for (int ci = 0; ci < 3; ++ci) {
        #pragma unroll 1
        for (int dy = 0; dy < 3; ++dy) {
            const int iy = oy * 2 + dy;
            float v0 = 0.f, v1 = 0.f, v2 = 0.f;
            if (iy < HIN) {
                const float* row = xb + (size_t)ci * HIN * WIN + (size_t)iy * WIN + ix0;
                float2 p = *(const float2*)row;
                v0 = p.x; v1 = p.y;
                v2 = (ix0 + 2 < WIN) ? row[2] : 0.f;
            }
            const float vv[3] = {v0, v1, v2};
            #pragma unroll
            for (int dx = 0; dx < 3; ++dx) {
                const float v = vv[dx];
                const float* wr = &ew[ci * 9 + dy * 3 + dx][0];
                #pragma unroll
                for (int q = 0; q < 16; ++q) {
                    float4 wq = *(const float4*)(wr + q * 4);
                    acc[q*4+0] = fmaf(v, wq.x, acc[q*4+0]);
                    acc[q*4+1] = fmaf(v, wq.y, acc[q*4+1]);
                    acc[q*4+2] = fmaf(v, wq.z, acc[q*4+2]);
                    acc[q*4+3] = fmaf(v, wq.w, acc[q*4+3]);
                }
            }
        }
    }
    bf16_t* fp = f + ((size_t)z * HP * WP + (size_t)(oy + 1) * WP + (ox + 1)) * 64;
    #pragma unroll
    for (int g = 0; g < 8; ++g) {
        float r0 = acc[g*8+0], r1 = acc[g*8+1], r2 = acc[g*8+2], r3 = acc[g*8+3];
        float r4 = acc[g*8+4], r5 = acc[g*8+5], r6 = acc[g*8+6], r7 = acc[g*8+7];
        r0 = r0 > 0.f ? r0 : 0.f;  r1 = r1 > 0.f ? r1 : 0.f;
        r2 = r2 > 0.f ? r2 : 0.f;  r3 = r3 > 0.f ? r3 : 0.f;
        r4 = r4 > 0.f ? r4 : 0.f;  r5 = r5 > 0.f ? r5 : 0.f;
        r6 = r6 > 0.f ? r6 : 0.f;  r7 = r7 > 0.f ? r7 : 0.f;
        *(uint4*)(fp + g * 8) = make_uint4(pack2(r0,r1), pack2(r2,r3),
                                           pack2(r4,r5), pack2(r6,r7));
    }
}

// ---------- decoder (MFMA): f padded NHWC -> d padded NHWC, 3x3 conv 64->64 + bias + relu ----------
// 128 threads = 2 waves; block tile 16x16 px, all 64 co.
// wave w: rows w*8 .. w*8+7 (8 M-frags of 16 px). N = 64 co = 4 N-frags, co = 4*(lane&15)+n.
// A from swizzled LDS bf16 tile; B from global (fragment-packed) in regs, double-buffered per tap.
__global__ __launch_bounds__(128, 2) void decoder_mfma(
    const bf16_t* __restrict__ f, const bf16_t* __restrict__ wB,
    const float* __restrict__ dec_b, bf16_t* __restrict__ d)
{
    __shared__ __align__(16) bf16_t tile[18 * 18 * 64];   // 41,472 B, swizzled per pixel

    const int tid = threadIdx.x;
    const int w   = tid >> 6;
    const int l   = tid & 63;
    const int z   = blockIdx.z;
    const int y0  = blockIdx.y << 4, x0 = blockIdx.x << 4;

    // bias for this lane's 4 co (co = 4*(l&15)+n), hoisted early
    const int c4 = 4 * (l & 15);
    float bias0 = dec_b[c4 + 0], bias1 = dec_b[c4 + 1];
    float bias2 = dec_b[c4 + 2], bias3 = dec_b[c4 + 3];

    // ---- stage 18x18x64 bf16 tile (41.5 KB), XOR-swizzled within each 128B pixel ----
    const bf16_t* fbase = f + ((size_t)z * HP * WP + (size_t)y0 * WP + x0) * 64;
    for (int i = tid; i < 2592; i += 128) {          // (yy*18+xx)*8 + q
        int yy  = i / 144;
        int rem = i - yy * 144;
        int xx  = rem >> 3, q = rem & 7;
        int p   = yy * 18 + xx;
        uint4 v = *(const uint4*)(fbase + ((size_t)yy * WP + xx) * 64 + q * 8);
        int byteoff = (p * 128 + q * 16) ^ ((p & 7) << 4);
        *(uint4*)((char*)tile + byteoff) = v;
    }

    f32x4 acc[8][4];
    #pragma unroll
    for (int m = 0; m < 8; ++m)
        #pragma unroll
        for (int n = 0; n < 4; ++n)
            acc[m][n] = (f32x4){0.f, 0.f, 0.f, 0.f};

    const bf16x8* wBv = (const bf16x8*)wB;   // frag index: ((r*2+kc)*4+n)*64 + l
    bf16x8 B[2][2][4];
    #pragma unroll
    for (int kc = 0; kc < 2; ++kc)
        #pragma unroll
        for (int n = 0; n < 4; ++n)
            B[0][kc][n] = wBv[(kc * 4 + n) * 64 + l];

    __syncthreads();

    const int rowbase = w * 8;
    const int kg16 = (l >> 4) << 4;    // k-group byte offset
    const int xlane = l & 15;

    #pragma unroll
    for (int r = 0; r < 9; ++r) {
        const int dy = r / 3, dx = r - 3 * (r / 3);
        if (r < 8) {
            #pragma unroll
            for (int kc = 0; kc < 2; ++kc)
                #pragma unroll
                for (int n = 0; n < 4; ++n)
                    B[(r + 1) & 1][kc][n] = wBv[(((r + 1) * 2 + kc) * 4 + n) * 64 + l];
        }
        #pragma unroll
        for (int m = 0; m < 8; ++m) {
            const int p    = (rowbase + m + dy) * 18 + dx + xlane;
            const int swz  = (p & 7) << 4;
            const int base = p * 128 + kg16;
            bf16x8 a0 = *(const bf16x8*)((const char*)tile + ((base     ) ^ swz));
            bf16x8 a1 = *(const bf16x8*)((const char*)tile + ((base + 64) ^ swz));
            acc[m][0] = __builtin_amdgcn_mfma_f32_16x16x32_bf16(a0, B[r & 1][0][0], acc[m][0], 0, 0, 0);
            acc[m][1] = __builtin_amdgcn_mfma_f32_16x16x32_bf16(a0, B[r & 1][0][1], acc[m][1], 0, 0, 0);
            acc[m][2] = __builtin_amdgcn_mfma_f32_16x16x32_bf16(a0, B[r & 1][0][2], acc[m][2], 0, 0, 0);
            acc[m][3] = __builtin_amdgcn_mfma_f32_16x16x32_bf16(a0, B[r & 1][0][3], acc[m][3], 0, 0, 0);
            acc[m][0] = __builtin_amdgcn_mfma_f32_16x16x32_bf16(a1, B[r & 1][1][0], acc[m][0], 0, 0, 0);
            acc[m][1] = __builtin_amdgcn_mfma_f32_16x16x32_bf16(a1, B[r & 1][1][1], acc[m][1], 0, 0, 0);
            acc[m][2] = __builtin_amdgcn_mfma_f32_16x16x32_bf16(a1, B[r & 1][1][2], acc[m][2], 0, 0, 0);
            acc[m][3] = __builtin_amdgcn_mfma_f32_16x16x32_bf16(a1, B[r & 1][1][3], acc[m][3], 0, 0, 0);
        }
    }

    // ---- epilogue: bias + relu + pack, direct 8B stores (co contiguous per lane) ----
    bf16_t* dbase = d + (size_t)z * HP * WP * 64;
    const int xq = (l >> 4) * 4;
    #pragma unroll
    for (int m = 0; m < 8; ++m) {
        const int y = y0 + rowbase + m + 1;
        #pragma unroll
        for (int rr = 0; rr < 4; ++rr) {
            const int xg = x0 + xq + rr + 1;
            float v0 = acc[m][0][rr] + bias0;  v0 = v0 > 0.f ? v0 : 0.f;
            float v1 = acc[m][1][rr] + bias1;  v1 = v1 > 0.f ? v1 : 0.f;
            float v2 = acc[m][2][rr] + bias2;  v2 = v2 > 0.f ? v2 : 0.f;
            float v3 = acc[m][3][rr] + bias3;  v3 = v3 > 0.f ? v3 : 0.f;
            *(uint2*)(dbase + ((size_t)y * WP + xg) * 64 + c4) =
                make_uint2(pack2(v0, v1), pack2(v2, v3));
        }
    }
}

// ---------- head: d padded NHWC -> out f32, per-sample routed 3x3 conv 64->1 + bias ----------
__global__ __launch_bounds__(256) void head_kernel(
    const bf16_t* __restrict__ d, const float* __restrict__ head_w,
    const float* __restrict__ head_b, const int* __restrict__ cls_id,
    float* __restrict__ out, int b0)
{
    __shared__ __align__(16) bf16_t tile[18 * 18 * 64];
    __shared__ float hw[9][64];

    const int tid = threadIdx.x;
    const int z   = blockIdx.z;
    const int b   = b0 + z;
    const int y0  = blockIdx.y << 4, x0 = blockIdx.x << 4;
    const int cls = cls_id[b];

    for (int i = tid; i < 576; i += 256) {
        int r = i >> 6, ci = i & 63;
        hw[r][ci] = head_w[((size_t)cls * 64 + ci) * 9 + r];
    }
    const bf16_t* dbase = d + ((size_t)z * HP * WP + (size_t)y0 * WP + x0) * 64;
    for (int i = tid; i < 2592; i += 256) {
        int yy  = i / 144;
        int rem = i - yy * 144;
        int xx  = rem >> 3, q = rem & 7;
        int p   = yy * 18 + xx;
        uint4 v = *(const uint4*)(dbase + ((size_t)yy * WP + xx) * 64 + q * 8);
        int byteoff = (p * 128 + q * 16) ^ ((p & 7) << 4);
        *(uint4*)((char*)tile + byteoff) = v;
    }
    __syncthreads();

    const int py = tid >> 4, px = tid & 15;
    float acc = head_b[cls];
    #pragma unroll 1
    for (int r = 0; r < 9; ++r) {
        const int dy = r / 3, dx = r - 3 * (r / 3);
        const int p  = (py + dy) * 18 + px + dx;
        const int swz = (p & 7) << 4;
        const float* wr = &hw[r][0];
        #pragma unroll
        for (int q = 0; q < 8; ++q) {
            uint4 v = *(const uint4*)((const char*)tile + ((p * 128 + q * 16) ^ swz));
            float4 w0 = *(const float4*)(wr + q * 8);
            float4 w1 = *(const float4*)(wr + q * 8 + 4);
            acc = fmaf(bf_lo(v.x), w0.x, acc);
            acc = fmaf(bf_hi(v.x), w0.y, acc);
            acc = fmaf(bf_lo(v.y), w0.z, acc);
            acc = fmaf(bf_hi(v.y), w0.w, acc);
            acc = fmaf(bf_lo(v.z), w1.x, acc);
            acc = fmaf(bf_hi(v.z), w1.y, acc);
            acc = fmaf(bf_lo(v.w), w1.z, acc);
            acc = fmaf(bf_hi(v.w), w1.w, acc);
        }
    }
    out[(size_t)b * (HO * WO) + (size_t)(y0 + py) * WO + (x0 + px)] = acc;
}

extern "C" void kernel_launch(void* const* d_in, const int* in_sizes, int n_in,
                              void* d_out, int out_size, void* d_ws, size_t ws_size,
                              hipStream_t stream) {
    const float* x      = (const float*)d_in[0];
    const int*   cls_id = (const int*)  d_in[1];
    const float* enc_w  = (const float*)d_in[2];
    const float* enc_b  = (const float*)d_in[3];
    const float* dec_w  = (const float*)d_in[4];
    const float* dec_b  = (const float*)d_in[5];
    const float* head_w = (const float*)d_in[6];
    const float* head_b = (const float*)d_in[7];
    float* out = (float*)d_out;

    // ws layout: [wB 128KB][fbuf C imgs][dbuf C imgs], padded NHWC bf16 per image
    const size_t WB_RESERVE = 131072;
    const size_t PER_IMG    = (size_t)HP * WP * 64 * 2;   // 8,519,424 B
    char* ws = (char*)d_ws;
    bf16_t* wB = (bf16_t*)ws;

    size_t avail = (ws_size > WB_RESERVE) ? (ws_size - WB_RESERVE) : 0;
    int C = (int)(avail / (2 * PER_IMG));
    if (C < 1) C = 1;
    if (C > NIMG) C = NIMG;

    bf16_t* fbuf = (bf16_t*)(ws + WB_RESERVE);
    bf16_t* dbuf = (bf16_t*)(ws + WB_RESERVE + (size_t)C * PER_IMG);

    repack_decw<<<dim3(144), 256, 0, stream>>>(dec_w, wB);
    {
        int nthr = C * 1028 * 8;
        int nblk = (nthr + 255) / 256;
        zero_halo<<<dim3(nblk), 256, 0, stream>>>(fbuf, C);
        zero_halo<<<dim3(nblk), 256, 0, stream>>>(dbuf, C);
    }

    for (int b0 = 0; b0 < NIMG; b0 += C) {
        const int n = (NIMG - b0 < C) ? (NIMG - b0) : C;
        encoder_kernel<<<dim3(16, 16, n), 256, 0, stream>>>(x, enc_w, enc_b, fbuf, b0);
        decoder_mfma  <<<dim3(16, 16, n), 128, 0, stream>>>(fbuf, wB, dec_b, dbuf);
        head_kernel   <<<dim3(16, 16, n), 256, 0, stream>>>(dbuf, head_w, head_b, cls_id, out, b0);
    }
}

// Round 5
// 343.988 us; speedup vs baseline: 3.1407x; 1.9749x over previous
//
#include <hip/hip_runtime.h>
#include <stdint.h>

#define NIMG 16
#define HIN 512
#define WIN 512
#define HO 256
#define WO 256
#define HP 258
#define WP 258

typedef unsigned short bf16_t;
typedef unsigned int u32;
typedef short bf16x8 __attribute__((ext_vector_type(8)));
typedef float f32x4 __attribute__((ext_vector_type(4)));

// ---------- bf16 helpers ----------
static __device__ __forceinline__ bf16_t f2bf(float f) {
    u32 u = __float_as_uint(f);
    u += 0x7FFFu + ((u >> 16) & 1u);   // RNE
    return (bf16_t)(u >> 16);
}
static __device__ __forceinline__ float bf_lo(u32 u) { return __uint_as_float(u << 16); }
static __device__ __forceinline__ float bf_hi(u32 u) { return __uint_as_float(u & 0xFFFF0000u); }
static __device__ __forceinline__ u32 pack2(float a, float b) {
    return (u32)f2bf(a) | ((u32)f2bf(b) << 16);
}

// ---------- repack dec_w [co][ci][3][3] f32 -> wB bf16 in MFMA B-fragment order ----------
// wB[(8r+4kc+2q+n)*64 + l][j] = w[co = q*32 + 2*(l&15) + n][ci = kc*32 + (l>>4)*8 + j][r]
__global__ void repack_decw(const float* __restrict__ dec_w, bf16_t* __restrict__ wB) {
    int i = blockIdx.x * 256 + threadIdx.x;   // 9*2*2*2*64*8 = 36864
    if (i >= 36864) return;
    int j  = i & 7;
    int l  = (i >> 3) & 63;
    int n  = (i >> 9) & 1;
    int q  = (i >> 10) & 1;
    int kc = (i >> 11) & 1;
    int r  = i >> 12;
    int co = q * 32 + 2 * (l & 15) + n;
    int ci = kc * 32 + (l >> 4) * 8 + j;
    wB[i] = f2bf(dec_w[(co * 64 + ci) * 9 + r]);
}

// ---------- zero the 1-px halo of a padded NHWC [nimg][258][258][64] bf16 buffer ----------
__global__ void zero_halo(bf16_t* __restrict__ buf, int nimg) {
    const int per_img = 1028 * 8;   // border pixels * 8 chunks of 16B
    int i = blockIdx.x * 256 + threadIdx.x;
    if (i >= nimg * per_img) return;
    int z = i / per_img;
    int rem = i - z * per_img;
    int p = rem >> 3, q = rem & 7;
    int row, col;
    if (p < 258)      { row = 0;           col = p; }
    else if (p < 516) { row = 257;         col = p - 258; }
    else if (p < 772) { row = p - 516 + 1; col = 0; }
    else              { row = p - 772 + 1; col = 257; }
    *(uint4*)(buf + ((size_t)z * HP * WP + (size_t)row * WP + col) * 64 + q * 8) =
        make_uint4(0u, 0u, 0u, 0u);
}

// ---------- encoder: x[b][3][512][512] f32 -> f[z][258][258][64] bf16 (padded NHWC) ----------
__global__ __launch_bounds__(256) void encoder_kernel(
    const float* __restrict__ x, const float* __restrict__ enc_w,
    const float* __restrict__ enc_b, bf16_t* __restrict__ f, int b0)
{
    __shared__ __align__(16) float ew[27][64];
    __shared__ float eb[64];
    __shared__ __align__(16) u32 ot[256 * 37];   // pixel-stride 37 words: bank-conflict-free
    const int tid = threadIdx.x;
    for (int i = tid; i < 27 * 64; i += 256) {
        int co = i & 63, qq = i >> 6;
        ew[qq][co] = enc_w[co * 27 + qq];
    }
    if (tid < 64) eb[tid] = enc_b[tid];
    __syncthreads();

    const int z  = blockIdx.z;
    const int b  = b0 + z;
    const int oy = (blockIdx.y << 4) + (tid >> 4);
    const int ox = (blockIdx.x << 4) + (tid & 15);
    const int ix0 = ox * 2;

    float acc[64];
    #pragma unroll
    for (int c = 0; c < 64; ++c) acc[c] = eb[c];

    const float* xb = x + (size_t)b * 3 * HIN * WIN;
    #pragma unroll 1
    for (int ci = 0; ci < 3; ++ci) {
        #pragma unroll 1
        for (int dy = 0; dy < 3; ++dy) {
            const int iy = oy * 2 + dy;
            float v0 = 0.f, v1 = 0.f, v2 = 0.f;
            if (iy < HIN) {
                const float* row = xb + (size_t)ci * HIN * WIN + (size_t)iy * WIN + ix0;
                float2 p = *(const float2*)row;
                v0 = p.x; v1 = p.y;
                v2 = (ix0 + 2 < WIN) ? row[2] : 0.f;
            }
            const float vv[3] = {v0, v1, v2};
            #pragma unroll
            for (int dx = 0; dx < 3; ++dx) {
                const float v = vv[dx];
                const float* wr = &ew[ci * 9 + dy * 3 + dx][0];
                #pragma unroll
                for (int qq = 0; qq < 16; ++qq) {
                    float4 wq = *(const float4*)(wr + qq * 4);
                    acc[qq*4+0] = fmaf(v, wq.x, acc[qq*4+0]);
                    acc[qq*4+1] = fmaf(v, wq.y, acc[qq*4+1]);
                    acc[qq*4+2] = fmaf(v, wq.z, acc[qq*4+2]);
                    acc[qq*4+3] = fmaf(v, wq.w, acc[qq*4+3]);
                }
            }
        }
    }

    // ---- bounce through LDS, then cooperative contiguous stores ----
    #pragma unroll
    for (int c = 0; c < 32; ++c) {
        float a0 = acc[2*c+0]; a0 = a0 > 0.f ? a0 : 0.f;
        float a1 = acc[2*c+1]; a1 = a1 > 0.f ? a1 : 0.f;
        ot[tid * 37 + c] = pack2(a0, a1);
    }
    __syncthreads();
    bf16_t* fz = f + (size_t)z * HP * WP * 64;
    const int by = blockIdx.y << 4, bx = blockIdx.x << 4;
    #pragma unroll
    for (int it = 0; it < 32; ++it) {
        int i = it * 256 + tid;
        int p = i >> 5, c = i & 31;
        u32 v = ot[p * 37 + c];
        int py = p >> 4, px = p & 15;
        *((u32*)(fz + ((size_t)(by + py + 1) * WP + (bx + px + 1)) * 64) + c) = v;
    }
}

// ---------- decoder (MFMA): 256 thr = 4 waves; wave (h,q): rows h*8..h*8+7, co-half q ----------
// acc[8][2] f32x4 = 64 VGPR/thread. A from swizzled LDS; B fragment-packed from L2, dbuf per tap.
__global__ __launch_bounds__(256) void decoder_mfma(
    const bf16_t* __restrict__ f, const bf16_t* __restrict__ wB,
    const float* __restrict__ dec_b, bf16_t* __restrict__ d)
{
    __shared__ __align__(16) bf16_t tile[18 * 18 * 64];   // 41472 B; reused as u32 ot[256*37]

    const int tid = threadIdx.x;
    const int w   = tid >> 6;
    const int h   = w >> 1;          // row half
    const int q   = w & 1;           // co half
    const int l   = tid & 63;
    const int z   = blockIdx.z;
    const int y0  = blockIdx.y << 4, x0 = blockIdx.x << 4;

    const int cb = q * 32 + 2 * (l & 15);
    const float bias0 = dec_b[cb], bias1 = dec_b[cb + 1];

    // B frag prefetch for tap r=0
    const bf16x8* wBv = (const bf16x8*)wB;
    bf16x8 B[2][2][2];   // [parity][kc][n]
    #pragma unroll
    for (int kc = 0; kc < 2; ++kc)
        #pragma unroll
        for (int n = 0; n < 2; ++n)
            B[0][kc][n] = wBv[((4 * kc + 2 * q + n) << 6) + l];

    // ---- stage 18x18x64 bf16 tile, XOR-swizzled within each 128B pixel ----
    const bf16_t* fbase = f + ((size_t)z * HP * WP + (size_t)y0 * WP + x0) * 64;
    for (int i = tid; i < 2592; i += 256) {
        int yy  = i / 144;
        int rem = i - yy * 144;
        int xx  = rem >> 3, qq = rem & 7;
        int p   = yy * 18 + xx;
        uint4 v = *(const uint4*)(fbase + ((size_t)yy * WP + xx) * 64 + qq * 8);
        int byteoff = (p * 128 + qq * 16) ^ ((p & 7) << 4);
        *(uint4*)((char*)tile + byteoff) = v;
    }

    f32x4 acc[8][2];
    #pragma unroll
    for (int m = 0; m < 8; ++m) {
        acc[m][0] = (f32x4){0.f, 0.f, 0.f, 0.f};
        acc[m][1] = (f32x4){0.f, 0.f, 0.f, 0.f};
    }

    __syncthreads();

    const int rowbase = h * 8;
    const int kg16 = (l >> 4) << 4;
    const int xlane = l & 15;

    #pragma unroll
    for (int r = 0; r < 9; ++r) {
        const int dy = r / 3, dx = r - 3 * (r / 3);
        if (r < 8) {
            #pragma unroll
            for (int kc = 0; kc < 2; ++kc)
                #pragma unroll
                for (int n = 0; n < 2; ++n)
                    B[(r + 1) & 1][kc][n] = wBv[((8 * (r + 1) + 4 * kc + 2 * q + n) << 6) + l];
        }
        #pragma unroll
        for (int m = 0; m < 8; ++m) {
            const int p    = (rowbase + m + dy) * 18 + dx + xlane;
            const int swz  = (p & 7) << 4;
            const int base = p * 128 + kg16;
            bf16x8 a0 = *(const bf16x8*)((const char*)tile + ((base     ) ^ swz));
            bf16x8 a1 = *(const bf16x8*)((const char*)tile + ((base + 64) ^ swz));
            acc[m][0] = __builtin_amdgcn_mfma_f32_16x16x32_bf16(a0, B[r & 1][0][0], acc[m][0], 0, 0, 0);
            acc[m][1] = __builtin_amdgcn_mfma_f32_16x16x32_bf16(a0, B[r & 1][0][1], acc[m][1], 0, 0, 0);
            acc[m][0] = __builtin_amdgcn_mfma_f32_16x16x32_bf16(a1, B[r & 1][1][0], acc[m][0], 0, 0, 0);
            acc[m][1] = __builtin_amdgcn_mfma_f32_16x16x32_bf16(a1, B[r & 1][1][1], acc[m][1], 0, 0, 0);
        }
    }

    // ---- epilogue: bias+relu -> LDS (stride-37 pixel layout) -> contiguous stores ----
    __syncthreads();   // all waves done reading A
    u32* ot = (u32*)tile;
    #pragma unroll
    for (int m = 0; m < 8; ++m) {
        #pragma unroll
        for (int rr = 0; rr < 4; ++rr) {
            const int p = (rowbase + m) * 16 + (l >> 4) * 4 + rr;
            float v0 = acc[m][0][rr] + bias0;  v0 = v0 > 0.f ? v0 : 0.f;
            float v1 = acc[m][1][rr] + bias1;  v1 = v1 > 0.f ? v1 : 0.f;
            ot[p * 37 + q * 16 + (l & 15)] = pack2(v0, v1);
        }
    }
    __syncthreads();

    bf16_t* dz = d + (size_t)z * HP * WP * 64;
    #pragma unroll
    for (int it = 0; it < 32; ++it) {
        int i = it * 256 + tid;
        int p = i >> 5, c = i & 31;
        u32 v = ot[p * 37 + c];
        int py = p >> 4, px = p & 15;
        *((u32*)(dz + ((size_t)(y0 + py + 1) * WP + (x0 + px + 1)) * 64) + c) = v;
    }
}

// ---------- head: d padded NHWC -> out f32, per-sample routed 3x3 conv 64->1 + bias ----------
__global__ __launch_bounds__(256) void head_kernel(
    const bf16_t* __restrict__ d, const float* __restrict__ head_w,
    const float* __restrict__ head_b, const int* __restrict__ cls_id,
    float* __restrict__ out, int b0)
{
    __shared__ __align__(16) bf16_t tile[18 * 18 * 64];
    __shared__ float hw[9][64];

    const int tid = threadIdx.x;
    const int z   = blockIdx.z;
    const int b   = b0 + z;
    const int y0  = blockIdx.y << 4, x0 = blockIdx.x << 4;
    const int cls = cls_id[b];

    for (int i = tid; i < 576; i += 256) {
        int r = i >> 6, ci = i & 63;
        hw[r][ci] = head_w[((size_t)cls * 64 + ci) * 9 + r];
    }
    const bf16_t* dbase = d + ((size_t)z * HP * WP + (size_t)y0 * WP + x0) * 64;
    for (int i = tid; i < 2592; i += 256) {
        int yy  = i / 144;
        int rem = i - yy * 144;
        int xx  = rem >> 3, q = rem & 7;
        int p   = yy * 18 + xx;
        uint4 v = *(const uint4*)(dbase + ((size_t)yy * WP + xx) * 64 + q * 8);
        int byteoff = (p * 128 + q * 16) ^ ((p & 7) << 4);
        *(uint4*)((char*)tile + byteoff) = v;
    }
    __syncthreads();

    const int py = tid >> 4, px = tid & 15;
    float acc = head_b[cls];
    #pragma unroll 1
    for (int r = 0; r < 9; ++r) {
        const int dy = r / 3, dx = r - 3 * (r / 3);
        const int p  = (py + dy) * 18 + px + dx;
        const int swz = (p & 7) << 4;
        const float* wr = &hw[r][0];
        #pragma unroll
        for (int q = 0; q < 8; ++q) {
            uint4 v = *(const uint4*)((const char*)tile + ((p * 128 + q * 16) ^ swz));
            float4 w0 = *(const float4*)(wr + q * 8);
            float4 w1 = *(const float4*)(wr + q * 8 + 4);
            acc = fmaf(bf_lo(v.x), w0.x, acc);
            acc = fmaf(bf_hi(v.x), w0.y, acc);
            acc = fmaf(bf_lo(v.y), w0.z, acc);
            acc = fmaf(bf_hi(v.y), w0.w, acc);
            acc = fmaf(bf_lo(v.z), w1.x, acc);
            acc = fmaf(bf_hi(v.z), w1.y, acc);
            acc = fmaf(bf_lo(v.w), w1.z, acc);
            acc = fmaf(bf_hi(v.w), w1.w, acc);
        }
    }
    out[(size_t)b * (HO * WO) + (size_t)(y0 + py) * WO + (x0 + px)] = acc;
}

extern "C" void kernel_launch(void* const* d_in, const int* in_sizes, int n_in,
                              void* d_out, int out_size, void* d_ws, size_t ws_size,
                              hipStream_t stream) {
    const float* x      = (const float*)d_in[0];
    const int*   cls_id = (const int*)  d_in[1];
    const float* enc_w  = (const float*)d_in[2];
    const float* enc_b  = (const float*)d_in[3];
    const float* dec_w  = (const float*)d_in[4];
    const float* dec_b  = (const float*)d_in[5];
    const float* head_w = (const float*)d_in[6];
    const float* head_b = (const float*)d_in[7];
    float* out = (float*)d_out;

    const size_t WB_RESERVE = 131072;
    const size_t PER_IMG    = (size_t)HP * WP * 64 * 2;   // 8,519,424 B
    char* ws = (char*)d_ws;
    bf16_t* wB = (bf16_t*)ws;

    size_t avail = (ws_size > WB_RESERVE) ? (ws_size - WB_RESERVE) : 0;
    int C = (int)(avail / (2 * PER_IMG));
    if (C < 1) C = 1;
    if (C > NIMG) C = NIMG;

    bf16_t* fbuf = (bf16_t*)(ws + WB_RESERVE);
    bf16_t* dbuf = (bf16_t*)(ws + WB_RESERVE + (size_t)C * PER_IMG);

    repack_decw<<<dim3(144), 256, 0, stream>>>(dec_w, wB);
    {
        int nthr = C * 1028 * 8;
        int nblk = (nthr + 255) / 256;
        zero_halo<<<dim3(nblk), 256, 0, stream>>>(fbuf, C);
        zero_halo<<<dim3(nblk), 256, 0, stream>>>(dbuf, C);
    }

    for (int b0 = 0; b0 < NIMG; b0 += C) {
        const int n = (NIMG - b0 < C) ? (NIMG - b0) : C;
        encoder_kernel<<<dim3(16, 16, n), 256, 0, stream>>>(x, enc_w, enc_b, fbuf, b0);
        decoder_mfma  <<<dim3(16, 16, n), 256, 0, stream>>>(fbuf, wB, dec_b, dbuf);
        head_kernel   <<<dim3(16, 16, n), 256, 0, stream>>>(dbuf, head_w, head_b, cls_id, out, b0);
    }
}

// Round 6
// 333.303 us; speedup vs baseline: 3.2414x; 1.0321x over previous
//
#include <hip/hip_runtime.h>
#include <stdint.h>

#define NIMG 16
#define HIN 512
#define WIN 512
#define HO 256
#define WO 256
#define HP 258
#define WP 258

typedef unsigned short bf16_t;
typedef unsigned int u32;
typedef short bf16x8 __attribute__((ext_vector_type(8)));
typedef float f32x4 __attribute__((ext_vector_type(4)));
typedef float f32x16 __attribute__((ext_vector_type(16)));

// ---------- bf16 helpers ----------
static __device__ __forceinline__ bf16_t f2bf(float f) {
    u32 u = __float_as_uint(f);
    u += 0x7FFFu + ((u >> 16) & 1u);   // RNE
    return (bf16_t)(u >> 16);
}
static __device__ __forceinline__ float bf_lo(u32 u) { return __uint_as_float(u << 16); }
static __device__ __forceinline__ float bf_hi(u32 u) { return __uint_as_float(u & 0xFFFF0000u); }
static __device__ __forceinline__ u32 pack2(float a, float b) {
    return (u32)f2bf(a) | ((u32)f2bf(b) << 16);
}

// ---------- repack dec_w [co][ci][3][3] f32 -> wB bf16, 32x32x16 B-fragment order ----------
// frag = (r*4+kc)*2+q ; wB[(frag*64 + l)*8 + j] = w[co=q*32+(l&31)][ci=kc*16+((l>>5)&1)*8+j][r]
__global__ void repack_decw(const float* __restrict__ dec_w, bf16_t* __restrict__ wB) {
    int i = blockIdx.x * 256 + threadIdx.x;   // 9*4*2*64*8 = 36864
    if (i >= 36864) return;
    int j  = i & 7;
    int l  = (i >> 3) & 63;
    int q  = (i >> 9) & 1;
    int kc = (i >> 10) & 3;
    int r  = i >> 12;
    int co = q * 32 + (l & 31);
    int ci = kc * 16 + ((l >> 5) & 1) * 8 + j;
    wB[i] = f2bf(dec_w[(co * 64 + ci) * 9 + r]);
}

// ---------- zero the 1-px halo of a padded NHWC [nimg][258][258][64] bf16 buffer ----------
__global__ void zero_halo(bf16_t* __restrict__ buf, int nimg) {
    const int per_img = 1028 * 8;   // border pixels * 8 chunks of 16B
    int i = blockIdx.x * 256 + threadIdx.x;
    if (i >= nimg * per_img) return;
    int z = i / per_img;
    int rem = i - z * per_img;
    int p = rem >> 3, q = rem & 7;
    int row, col;
    if (p < 258)      { row = 0;           col = p; }
    else if (p < 516) { row = 257;         col = p - 258; }
    else if (p < 772) { row = p - 516 + 1; col = 0; }
    else              { row = p - 772 + 1; col = 257; }
    *(uint4*)(buf + ((size_t)z * HP * WP + (size_t)row * WP + col) * 64 + q * 8) =
        make_uint4(0u, 0u, 0u, 0u);
}

// ---------- encoder: x[b][3][512][512] f32 -> f[z][258][258][64] bf16 (padded NHWC) ----------
__global__ __launch_bounds__(256) void encoder_kernel(
    const float* __restrict__ x, const float* __restrict__ enc_w,
    const float* __restrict__ enc_b, bf16_t* __restrict__ f, int b0)
{
    __shared__ __align__(16) float ew[27][64];
    __shared__ float eb[64];
    __shared__ __align__(16) u32 ot[256 * 37];   // pixel-stride 37 words: bank-conflict-free
    const int tid = threadIdx.x;
    for (int i = tid; i < 27 * 64; i += 256) {
        int co = i & 63, qq = i >> 6;
        ew[qq][co] = enc_w[co * 27 + qq];
    }
    if (tid < 64) eb[tid] = enc_b[tid];
    __syncthreads();

    const int z  = blockIdx.z;
    const int b  = b0 + z;
    const int oy = (blockIdx.y << 4) + (tid >> 4);
    const int ox = (blockIdx.x << 4) + (tid & 15);
    const int ix0 = ox * 2;

    float acc[64];
    #pragma unroll
    for (int c = 0; c < 64; ++c) acc[c] = eb[c];

    const float* xb = x + (size_t)b * 3 * HIN * WIN;
    #pragma unroll 1
    for (int ci = 0; ci < 3; ++ci) {
        #pragma unroll 1
        for (int dy = 0; dy < 3; ++dy) {
            const int iy = oy * 2 + dy;
            float v0 = 0.f, v1 = 0.f, v2 = 0.f;
            if (iy < HIN) {
                const float* row = xb + (size_t)ci * HIN * WIN + (size_t)iy * WIN + ix0;
                float2 p = *(const float2*)row;
                v0 = p.x; v1 = p.y;
                v2 = (ix0 + 2 < WIN) ? row[2] : 0.f;
            }
            const float vv[3] = {v0, v1, v2};
            #pragma unroll
            for (int dx = 0; dx < 3; ++dx) {
                const float v = vv[dx];
                const float* wr = &ew[ci * 9 + dy * 3 + dx][0];
                #pragma unroll
                for (int qq = 0; qq < 16; ++qq) {
                    float4 wq = *(const float4*)(wr + qq * 4);
                    acc[qq*4+0] = fmaf(v, wq.x, acc[qq*4+0]);
                    acc[qq*4+1] = fmaf(v, wq.y, acc[qq*4+1]);
                    acc[qq*4+2] = fmaf(v, wq.z, acc[qq*4+2]);
                    acc[qq*4+3] = fmaf(v, wq.w, acc[qq*4+3]);
                }
            }
        }
    }

    // ---- bounce through LDS, then cooperative contiguous stores ----
    #pragma unroll
    for (int c = 0; c < 32; ++c) {
        float a0 = acc[2*c+0]; a0 = a0 > 0.f ? a0 : 0.f;
        float a1 = acc[2*c+1]; a1 = a1 > 0.f ? a1 : 0.f;
        ot[tid * 37 + c] = pack2(a0, a1);
    }
    __syncthreads();
    bf16_t* fz = f + (size_t)z * HP * WP * 64;
    const int by = blockIdx.y << 4, bx = blockIdx.x << 4;
    #pragma unroll
    for (int it = 0; it < 32; ++it) {
        int i = it * 256 + tid;
        int p = i >> 5, c = i & 31;
        u32 v = ot[p * 37 + c];
        int py = p >> 4, px = p & 15;
        *((u32*)(fz + ((size_t)(by + py + 1) * WP + (bx + px + 1)) * 64) + c) = v;
    }
}

// ---------- decoder (MFMA 32x32x16): 256 thr = 4 waves ----------
// Wave w: M-frags {2w, 2w+1} (32 px each = image rows 4w..4w+3), both co-halves.
// acc[2][2] f32x16 = 64 VGPR. A from swizzled LDS; B fragment-packed from L2 per tap.
__global__ __launch_bounds__(256) void decoder_mfma(
    const bf16_t* __restrict__ f, const bf16_t* __restrict__ wB,
    const float* __restrict__ dec_b, bf16_t* __restrict__ d)
{
    __shared__ __align__(16) bf16_t tile[18 * 18 * 64];   // 41472 B; epilogue reuses as [256][72]

    const int tid = threadIdx.x;
    const int w   = tid >> 6;
    const int l   = tid & 63;
    const int z   = blockIdx.z;
    const int y0  = blockIdx.y << 4, x0 = blockIdx.x << 4;

    const int col = l & 31;
    const float bias0 = dec_b[col];        // q=0 co
    const float bias1 = dec_b[32 + col];   // q=1 co

    // ---- stage 18x18x64 bf16 tile, XOR-swizzled within each 128B pixel ----
    const bf16_t* fbase = f + ((size_t)z * HP * WP + (size_t)y0 * WP + x0) * 64;
    for (int i = tid; i < 2592; i += 256) {
        int yy  = i / 144;
        int rem = i - yy * 144;
        int xx  = rem >> 3, qq = rem & 7;
        int p   = yy * 18 + xx;
        uint4 v = *(const uint4*)(fbase + ((size_t)yy * WP + xx) * 64 + qq * 8);
        int byteoff = (p * 128 + qq * 16) ^ ((p & 7) << 4);
        *(uint4*)((char*)tile + byteoff) = v;
    }

    f32x16 acc[2][2];
    #pragma unroll
    for (int mf = 0; mf < 2; ++mf)
        #pragma unroll
        for (int q = 0; q < 2; ++q)
            acc[mf][q] = (f32x16){0.f,0.f,0.f,0.f,0.f,0.f,0.f,0.f,
                                  0.f,0.f,0.f,0.f,0.f,0.f,0.f,0.f};

    __syncthreads();

    const bf16x8* wBv = (const bf16x8*)wB;
    const int ty_l = (l >> 4) & 1;     // sub-row within M-frag
    const int tx_l = l & 15;           // pixel col
    const int kh16 = (l >> 5) << 4;    // k-half byte offset

    #pragma unroll
    for (int r = 0; r < 9; ++r) {
        const int dy = r / 3, dx = r - 3 * (r / 3);
        bf16x8 Bf[4][2];
        #pragma unroll
        for (int kc = 0; kc < 4; ++kc)
            #pragma unroll
            for (int q = 0; q < 2; ++q)
                Bf[kc][q] = wBv[(((r * 4 + kc) << 1) + q) * 64 + l];
        #pragma unroll
        for (int mf = 0; mf < 2; ++mf) {
            const int p   = (4 * w + 2 * mf + ty_l + dy) * 18 + tx_l + dx;
            const int swz = (p & 7) << 4;
            const int pb  = p * 128 + kh16;
            #pragma unroll
            for (int kc = 0; kc < 4; ++kc) {
                bf16x8 a = *(const bf16x8*)((const char*)tile + ((pb + kc * 32) ^ swz));
                acc[mf][0] = __builtin_amdgcn_mfma_f32_32x32x16_bf16(a, Bf[kc][0], acc[mf][0], 0, 0, 0);
                acc[mf][1] = __builtin_amdgcn_mfma_f32_32x32x16_bf16(a, Bf[kc][1], acc[mf][1], 0, 0, 0);
            }
        }
    }

    // ---- epilogue: bias+relu -> LDS bf16 [256 px][stride 72] -> contiguous stores ----
    __syncthreads();   // all waves done reading A from tile
    bf16_t* ot = tile;
    #pragma unroll
    for (int mf = 0; mf < 2; ++mf) {
        #pragma unroll
        for (int q = 0; q < 2; ++q) {
            const float bs = q ? bias1 : bias0;
            #pragma unroll
            for (int v = 0; v < 16; ++v) {
                const int grow = (v & 3) + 8 * (v >> 2) + 4 * (l >> 5);
                const int flat = (2 * w + mf) * 32 + grow;
                float t = acc[mf][q][v] + bs;
                t = t > 0.f ? t : 0.f;
                ot[flat * 72 + q * 32 + col] = f2bf(t);
            }
        }
    }
    __syncthreads();

    bf16_t* dz = d + (size_t)z * HP * WP * 64;
    #pragma unroll
    for (int it = 0; it < 32; ++it) {
        int i = it * 256 + tid;
        int p = i >> 5, c = i & 31;
        u32 v = *(const u32*)(ot + p * 72 + c * 2);
        int py = p >> 4, px = p & 15;
        *((u32*)(dz + ((size_t)(y0 + py + 1) * WP + (x0 + px + 1)) * 64) + c) = v;
    }
}

// ---------- head: d padded NHWC -> out f32, per-sample routed 3x3 conv 64->1 + bias ----------
__global__ __launch_bounds__(256) void head_kernel(
    const bf16_t* __restrict__ d, const float* __restrict__ head_w,
    const float* __restrict__ head_b, const int* __restrict__ cls_id,
    float* __restrict__ out, int b0)
{
    __shared__ __align__(16) bf16_t tile[18 * 18 * 64];
    __shared__ float hw[9][64];

    const int tid = threadIdx.x;
    const int z   = blockIdx.z;
    const int b   = b0 + z;
    const int y0  = blockIdx.y << 4, x0 = blockIdx.x << 4;
    const int cls = cls_id[b];

    for (int i = tid; i < 576; i += 256) {
        int r = i >> 6, ci = i & 63;
        hw[r][ci] = head_w[((size_t)cls * 64 + ci) * 9 + r];
    }
    const bf16_t* dbase = d + ((size_t)z * HP * WP + (size_t)y0 * WP + x0) * 64;
    for (int i = tid; i < 2592; i += 256) {
        int yy  = i / 144;
        int rem = i - yy * 144;
        int xx  = rem >> 3, q = rem & 7;
        int p   = yy * 18 + xx;
        uint4 v = *(const uint4*)(dbase + ((size_t)yy * WP + xx) * 64 + q * 8);
        int byteoff = (p * 128 + q * 16) ^ ((p & 7) << 4);
        *(uint4*)((char*)tile + byteoff) = v;
    }
    __syncthreads();

    const int py = tid >> 4, px = tid & 15;
    float acc = head_b[cls];
    #pragma unroll 1
    for (int r = 0; r < 9; ++r) {
        const int dy = r / 3, dx = r - 3 * (r / 3);
        const int p  = (py + dy) * 18 + px + dx;
        const int swz = (p & 7) << 4;
        const float* wr = &hw[r][0];
        #pragma unroll
        for (int q = 0; q < 8; ++q) {
            uint4 v = *(const uint4*)((const char*)tile + ((p * 128 + q * 16) ^ swz));
            float4 w0 = *(const float4*)(wr + q * 8);
            float4 w1 = *(const float4*)(wr + q * 8 + 4);
            acc = fmaf(bf_lo(v.x), w0.x, acc);
            acc = fmaf(bf_hi(v.x), w0.y, acc);
            acc = fmaf(bf_lo(v.y), w0.z, acc);
            acc = fmaf(bf_hi(v.y), w0.w, acc);
            acc = fmaf(bf_lo(v.z), w1.x, acc);
            acc = fmaf(bf_hi(v.z), w1.y, acc);
            acc = fmaf(bf_lo(v.w), w1.z, acc);
            acc = fmaf(bf_hi(v.w), w1.w, acc);
        }
    }
    out[(size_t)b * (HO * WO) + (size_t)(y0 + py) * WO + (x0 + px)] = acc;
}

extern "C" void kernel_launch(void* const* d_in, const int* in_sizes, int n_in,
                              void* d_out, int out_size, void* d_ws, size_t ws_size,
                              hipStream_t stream) {
    const float* x      = (const float*)d_in[0];
    const int*   cls_id = (const int*)  d_in[1];
    const float* enc_w  = (const float*)d_in[2];
    const float* enc_b  = (const float*)d_in[3];
    const float* dec_w  = (const float*)d_in[4];
    const float* dec_b  = (const float*)d_in[5];
    const float* head_w = (const float*)d_in[6];
    const float* head_b = (const float*)d_in[7];
    float* out = (float*)d_out;

    const size_t WB_RESERVE = 131072;
    const size_t PER_IMG    = (size_t)HP * WP * 64 * 2;   // 8,519,424 B
    char* ws = (char*)d_ws;
    bf16_t* wB = (bf16_t*)ws;

    size_t avail = (ws_size > WB_RESERVE) ? (ws_size - WB_RESERVE) : 0;
    int C = (int)(avail / (2 * PER_IMG));
    if (C < 1) C = 1;
    if (C > NIMG) C = NIMG;

    bf16_t* fbuf = (bf16_t*)(ws + WB_RESERVE);
    bf16_t* dbuf = (bf16_t*)(ws + WB_RESERVE + (size_t)C * PER_IMG);

    repack_decw<<<dim3(144), 256, 0, stream>>>(dec_w, wB);
    {
        int nthr = C * 1028 * 8;
        int nblk = (nthr + 255) / 256;
        zero_halo<<<dim3(nblk), 256, 0, stream>>>(fbuf, C);
        zero_halo<<<dim3(nblk), 256, 0, stream>>>(dbuf, C);
    }

    for (int b0 = 0; b0 < NIMG; b0 += C) {
        const int n = (NIMG - b0 < C) ? (NIMG - b0) : C;
        encoder_kernel<<<dim3(16, 16, n), 256, 0, stream>>>(x, enc_w, enc_b, fbuf, b0);
        decoder_mfma  <<<dim3(16, 16, n), 256, 0, stream>>>(fbuf, wB, dec_b, dbuf);
        head_kernel   <<<dim3(16, 16, n), 256, 0, stream>>>(dbuf, head_w, head_b, cls_id, out, b0);
    }
}

// Round 7
// 285.974 us; speedup vs baseline: 3.7778x; 1.1655x over previous
//
#include <hip/hip_runtime.h>
#include <stdint.h>

#define NIMG 16
#define HIN 512
#define WIN 512
#define HO 256
#define WO 256
#define HP 258
#define WP 258

typedef unsigned short bf16_t;
typedef unsigned int u32;
typedef short bf16x8 __attribute__((ext_vector_type(8)));
typedef float f32x4 __attribute__((ext_vector_type(4)));
typedef float f32x16 __attribute__((ext_vector_type(16)));

// ---------- bf16 helpers ----------
static __device__ __forceinline__ bf16_t f2bf(float f) {
    u32 u = __float_as_uint(f);
    u += 0x7FFFu + ((u >> 16) & 1u);   // RNE
    return (bf16_t)(u >> 16);
}
static __device__ __forceinline__ float bf_lo(u32 u) { return __uint_as_float(u << 16); }
static __device__ __forceinline__ float bf_hi(u32 u) { return __uint_as_float(u & 0xFFFF0000u); }
static __device__ __forceinline__ u32 pack2(float a, float b) {
    return (u32)f2bf(a) | ((u32)f2bf(b) << 16);
}

// ---------- repack dec_w [co][ci][3][3] f32 -> wB bf16, 32x32x16 B-fragment order ----------
// frag = (r*4+kc)*2+q ; wB[(frag*64 + l)*8 + j] = w[co=q*32+(l&31)][ci=kc*16+((l>>5)&1)*8+j][r]
__global__ void repack_decw(const float* __restrict__ dec_w, bf16_t* __restrict__ wB) {
    int i = blockIdx.x * 256 + threadIdx.x;   // 9*4*2*64*8 = 36864
    if (i >= 36864) return;
    int j  = i & 7;
    int l  = (i >> 3) & 63;
    int q  = (i >> 9) & 1;
    int kc = (i >> 10) & 3;
    int r  = i >> 12;
    int co = q * 32 + (l & 31);
    int ci = kc * 16 + ((l >> 5) & 1) * 8 + j;
    wB[i] = f2bf(dec_w[(co * 64 + ci) * 9 + r]);
}

// ---------- zero the 1-px halo of a padded NHWC [nimg][258][258][64] bf16 buffer ----------
__global__ void zero_halo(bf16_t* __restrict__ buf, int nimg) {
    const int per_img = 1028 * 8;   // border pixels * 8 chunks of 16B
    int i = blockIdx.x * 256 + threadIdx.x;
    if (i >= nimg * per_img) return;
    int z = i / per_img;
    int rem = i - z * per_img;
    int p = rem >> 3, q = rem & 7;
    int row, col;
    if (p < 258)      { row = 0;           col = p; }
    else if (p < 516) { row = 257;         col = p - 258; }
    else if (p < 772) { row = p - 516 + 1; col = 0; }
    else              { row = p - 772 + 1; col = 257; }
    *(uint4*)(buf + ((size_t)z * HP * WP + (size_t)row * WP + col) * 64 + q * 8) =
        make_uint4(0u, 0u, 0u, 0u);
}

// ---------- encoder: x[b][3][512][512] f32 -> f[z][258][258][64] bf16 (padded NHWC) ----------
// 512 threads: thread = (pixel, co-half). acc[32] keeps VGPR low for occupancy.
__global__ __launch_bounds__(512) void encoder_kernel(
    const float* __restrict__ x, const float* __restrict__ enc_w,
    const float* __restrict__ enc_b, bf16_t* __restrict__ f, int b0)
{
    __shared__ __align__(16) float ew[27][64];
    __shared__ float eb[64];
    __shared__ __align__(16) u32 ot[256 * 37];   // pixel-stride 37 words
    const int tid = threadIdx.x;
    for (int i = tid; i < 27 * 64; i += 512) {
        int co = i & 63, qq = i >> 6;
        ew[qq][co] = enc_w[co * 27 + qq];
    }
    if (tid < 64) eb[tid] = enc_b[tid];
    __syncthreads();

    const int z    = blockIdx.z;
    const int b    = b0 + z;
    const int half = tid & 1;
    const int px   = tid >> 1;               // 0..255
    const int oy = (blockIdx.y << 4) + (px >> 4);
    const int ox = (blockIdx.x << 4) + (px & 15);
    const int ix0 = ox * 2;

    float acc[32];
    #pragma unroll
    for (int c = 0; c < 32; ++c) acc[c] = eb[half * 32 + c];

    const float* xb = x + (size_t)b * 3 * HIN * WIN;
    #pragma unroll 1
    for (int ci = 0; ci < 3; ++ci) {
        #pragma unroll 1
        for (int dy = 0; dy < 3; ++dy) {
            const int iy = oy * 2 + dy;
            float v0 = 0.f, v1 = 0.f, v2 = 0.f;
            if (iy < HIN) {
                const float* row = xb + (size_t)ci * HIN * WIN + (size_t)iy * WIN + ix0;
                float2 p = *(const float2*)row;
                v0 = p.x; v1 = p.y;
                v2 = (ix0 + 2 < WIN) ? row[2] : 0.f;
            }
            const float vv[3] = {v0, v1, v2};
            #pragma unroll
            for (int dx = 0; dx < 3; ++dx) {
                const float v = vv[dx];
                const float* wr = &ew[ci * 9 + dy * 3 + dx][half * 32];
                #pragma unroll
                for (int qq = 0; qq < 8; ++qq) {
                    float4 wq = *(const float4*)(wr + qq * 4);
                    acc[qq*4+0] = fmaf(v, wq.x, acc[qq*4+0]);
                    acc[qq*4+1] = fmaf(v, wq.y, acc[qq*4+1]);
                    acc[qq*4+2] = fmaf(v, wq.z, acc[qq*4+2]);
                    acc[qq*4+3] = fmaf(v, wq.w, acc[qq*4+3]);
                }
            }
        }
    }

    // ---- bounce through LDS, then cooperative contiguous stores ----
    #pragma unroll
    for (int k = 0; k < 16; ++k) {
        float a0 = acc[2*k+0]; a0 = a0 > 0.f ? a0 : 0.f;
        float a1 = acc[2*k+1]; a1 = a1 > 0.f ? a1 : 0.f;
        ot[px * 37 + half * 16 + k] = pack2(a0, a1);
    }
    __syncthreads();
    bf16_t* fz = f + (size_t)z * HP * WP * 64;
    const int by = blockIdx.y << 4, bx = blockIdx.x << 4;
    #pragma unroll
    for (int it = 0; it < 16; ++it) {
        int i = it * 512 + tid;
        int p = i >> 5, c = i & 31;
        u32 v = ot[p * 37 + c];
        int py = p >> 4, pxx = p & 15;
        *((u32*)(fz + ((size_t)(by + py + 1) * WP + (bx + pxx + 1)) * 64) + c) = v;
    }
}

// ---------- decoder (MFMA 32x32x16): 512 thr = 8 waves, 16x16 tile ----------
// Wave w owns M-frag w = tile rows {2w, 2w+1} (32 px), both co-halves.
// acc[2] f32x16 = 32 VGPR. A from swizzled LDS; B fragment-packed from L2 per tap.
__global__ __launch_bounds__(512, 4) void decoder_mfma(
    const bf16_t* __restrict__ f, const bf16_t* __restrict__ wB,
    const float* __restrict__ dec_b, bf16_t* __restrict__ d)
{
    __shared__ __align__(16) bf16_t tile[18 * 18 * 64];   // 41,472 B; epilogue reuses as [256][72]

    const int tid = threadIdx.x;
    const int w   = tid >> 6;          // 0..7
    const int l   = tid & 63;
    const int z   = blockIdx.z;
    const int y0  = blockIdx.y << 4, x0 = blockIdx.x << 4;

    const int col = l & 31;
    const float bias0 = dec_b[col];        // q=0 co
    const float bias1 = dec_b[32 + col];   // q=1 co

    // ---- stage 18x18x64 bf16 tile, XOR-swizzled within each 128B pixel ----
    const bf16_t* fbase = f + ((size_t)z * HP * WP + (size_t)y0 * WP + x0) * 64;
    for (int i = tid; i < 2592; i += 512) {
        int p   = i >> 3, qq = i & 7;
        int yy  = p / 18, xx = p - yy * 18;
        uint4 v = *(const uint4*)(fbase + ((size_t)yy * WP + xx) * 64 + qq * 8);
        int byteoff = (p * 128 + qq * 16) ^ ((p & 7) << 4);
        *(uint4*)((char*)tile + byteoff) = v;
    }

    f32x16 acc[2];
    acc[0] = (f32x16){0.f,0.f,0.f,0.f,0.f,0.f,0.f,0.f,0.f,0.f,0.f,0.f,0.f,0.f,0.f,0.f};
    acc[1] = acc[0];

    __syncthreads();

    const bf16x8* wBv = (const bf16x8*)wB;
    const int ty_l = (l >> 4) & 1;     // sub-row within M-frag
    const int tx_l = l & 15;           // pixel col
    const int kh16 = (l >> 5) << 4;    // k-half byte offset

    #pragma unroll
    for (int r = 0; r < 9; ++r) {
        const int dy = r / 3, dx = r - 3 * (r / 3);
        bf16x8 Bf[4][2];
        #pragma unroll
        for (int kc = 0; kc < 4; ++kc) {
            Bf[kc][0] = wBv[(((r * 4 + kc) << 1) + 0) * 64 + l];
            Bf[kc][1] = wBv[(((r * 4 + kc) << 1) + 1) * 64 + l];
        }
        const int p   = (2 * w + ty_l + dy) * 18 + tx_l + dx;
        const int swz = (p & 7) << 4;
        const int pb  = p * 128 + kh16;
        #pragma unroll
        for (int kc = 0; kc < 4; ++kc) {
            bf16x8 a = *(const bf16x8*)((const char*)tile + ((pb + kc * 32) ^ swz));
            acc[0] = __builtin_amdgcn_mfma_f32_32x32x16_bf16(a, Bf[kc][0], acc[0], 0, 0, 0);
            acc[1] = __builtin_amdgcn_mfma_f32_32x32x16_bf16(a, Bf[kc][1], acc[1], 0, 0, 0);
        }
    }

    // ---- epilogue: bias+relu -> LDS bf16 [256 px][stride 72] -> contiguous stores ----
    __syncthreads();   // all waves done reading A from tile
    bf16_t* ot = tile;
    #pragma unroll
    for (int q = 0; q < 2; ++q) {
        const float bs = q ? bias1 : bias0;
        #pragma unroll
        for (int v = 0; v < 16; ++v) {
            const int grow = (v & 3) + 8 * (v >> 2) + 4 * (l >> 5);
            const int flat = w * 32 + grow;          // = py*16+px: py=2w+(grow>>4), px=grow&15
            float t = acc[q][v] + bs;
            t = t > 0.f ? t : 0.f;
            ot[flat * 72 + q * 32 + col] = f2bf(t);
        }
    }
    __syncthreads();

    bf16_t* dz = d + (size_t)z * HP * WP * 64;
    #pragma unroll
    for (int it = 0; it < 16; ++it) {
        int i = it * 512 + tid;
        int p = i >> 5, c = i & 31;
        u32 v = *(const u32*)(ot + p * 72 + c * 2);
        int py = p >> 4, pxx = p & 15;
        *((u32*)(dz + ((size_t)(y0 + py + 1) * WP + (x0 + pxx + 1)) * 64) + c) = v;
    }
}

// ---------- head: d padded NHWC -> out f32, per-sample routed 3x3 conv 64->1 + bias ----------
__global__ __launch_bounds__(256) void head_kernel(
    const bf16_t* __restrict__ d, const float* __restrict__ head_w,
    const float* __restrict__ head_b, const int* __restrict__ cls_id,
    float* __restrict__ out, int b0)
{
    __shared__ __align__(16) bf16_t tile[18 * 18 * 64];
    __shared__ float hw[9][64];

    const int tid = threadIdx.x;
    const int z   = blockIdx.z;
    const int b   = b0 + z;
    const int y0  = blockIdx.y << 4, x0 = blockIdx.x << 4;
    const int cls = cls_id[b];

    for (int i = tid; i < 576; i += 256) {
        int r = i >> 6, ci = i & 63;
        hw[r][ci] = head_w[((size_t)cls * 64 + ci) * 9 + r];
    }
    const bf16_t* dbase = d + ((size_t)z * HP * WP + (size_t)y0 * WP + x0) * 64;
    for (int i = tid; i < 2592; i += 256) {
        int yy  = i / 144;
        int rem = i - yy * 144;
        int xx  = rem >> 3, q = rem & 7;
        int p   = yy * 18 + xx;
        uint4 v = *(const uint4*)(dbase + ((size_t)yy * WP + xx) * 64 + q * 8);
        int byteoff = (p * 128 + q * 16) ^ ((p & 7) << 4);
        *(uint4*)((char*)tile + byteoff) = v;
    }
    __syncthreads();

    const int py = tid >> 4, px = tid & 15;
    float a0 = 0.f, a1 = 0.f, a2 = 0.f, a3 = 0.f;   // 4 chains to break fmaf dep latency
    #pragma unroll 1
    for (int r = 0; r < 9; ++r) {
        const int dy = r / 3, dx = r - 3 * (r / 3);
        const int p  = (py + dy) * 18 + px + dx;
        const int swz = (p & 7) << 4;
        const float* wr = &hw[r][0];
        #pragma unroll
        for (int q = 0; q < 8; ++q) {
            uint4 v = *(const uint4*)((const char*)tile + ((p * 128 + q * 16) ^ swz));
            float4 w0 = *(const float4*)(wr + q * 8);
            float4 w1 = *(const float4*)(wr + q * 8 + 4);
            float t0 = fmaf(bf_lo(v.x), w0.x, fmaf(bf_hi(v.x), w0.y, 0.f));
            float t1 = fmaf(bf_lo(v.y), w0.z, fmaf(bf_hi(v.y), w0.w, 0.f));
            float t2 = fmaf(bf_lo(v.z), w1.x, fmaf(bf_hi(v.z), w1.y, 0.f));
            float t3 = fmaf(bf_lo(v.w), w1.z, fmaf(bf_hi(v.w), w1.w, 0.f));
            a0 += t0; a1 += t1; a2 += t2; a3 += t3;
        }
    }
    const float acc = head_b[cls] + (a0 + a1) + (a2 + a3);
    out[(size_t)b * (HO * WO) + (size_t)(y0 + py) * WO + (x0 + px)] = acc;
}

extern "C" void kernel_launch(void* const* d_in, const int* in_sizes, int n_in,
                              void* d_out, int out_size, void* d_ws, size_t ws_size,
                              hipStream_t stream) {
    const float* x      = (const float*)d_in[0];
    const int*   cls_id = (const int*)  d_in[1];
    const float* enc_w  = (const float*)d_in[2];
    const float* enc_b  = (const float*)d_in[3];
    const float* dec_w  = (const float*)d_in[4];
    const float* dec_b  = (const float*)d_in[5];
    const float* head_w = (const float*)d_in[6];
    const float* head_b = (const float*)d_in[7];
    float* out = (float*)d_out;

    const size_t WB_RESERVE = 131072;
    const size_t PER_IMG    = (size_t)HP * WP * 64 * 2;   // 8,519,424 B
    char* ws = (char*)d_ws;
    bf16_t* wB = (bf16_t*)ws;

    size_t avail = (ws_size > WB_RESERVE) ? (ws_size - WB_RESERVE) : 0;
    int C = (int)(avail / (2 * PER_IMG));
    if (C < 1) C = 1;
    if (C > NIMG) C = NIMG;

    bf16_t* fbuf = (bf16_t*)(ws + WB_RESERVE);
    bf16_t* dbuf = (bf16_t*)(ws + WB_RESERVE + (size_t)C * PER_IMG);

    repack_decw<<<dim3(144), 256, 0, stream>>>(dec_w, wB);
    {
        int nthr = C * 1028 * 8;
        int nblk = (nthr + 255) / 256;
        zero_halo<<<dim3(nblk), 256, 0, stream>>>(fbuf, C);
        zero_halo<<<dim3(nblk), 256, 0, stream>>>(dbuf, C);
    }

    // balanced chunking: e.g. C=15 -> 2 rounds of 8 instead of 15+1
    int n_rounds = (NIMG + C - 1) / C;
    int per = (NIMG + n_rounds - 1) / n_rounds;
    for (int b0 = 0; b0 < NIMG; b0 += per) {
        const int n = (NIMG - b0 < per) ? (NIMG - b0) : per;
        encoder_kernel<<<dim3(16, 16, n), 512, 0, stream>>>(x, enc_w, enc_b, fbuf, b0);
        decoder_mfma  <<<dim3(16, 16, n), 512, 0, stream>>>(fbuf, wB, dec_b, dbuf);
        head_kernel   <<<dim3(16, 16, n), 256, 0, stream>>>(dbuf, head_w, head_b, cls_id, out, b0);
    }
}

// Round 8
// 239.544 us; speedup vs baseline: 4.5101x; 1.1938x over previous
//
#include <hip/hip_runtime.h>
#include <stdint.h>

#define NIMG 16
#define HIN 512
#define WIN 512
#define HO 256
#define WO 256
#define HP 258
#define WP 258

typedef unsigned short bf16_t;
typedef unsigned int u32;
typedef short bf16x8 __attribute__((ext_vector_type(8)));
typedef float f32x4 __attribute__((ext_vector_type(4)));
typedef float f32x16 __attribute__((ext_vector_type(16)));

// ---------- bf16 helpers ----------
static __device__ __forceinline__ bf16_t f2bf(float f) {
    u32 u = __float_as_uint(f);
    u += 0x7FFFu + ((u >> 16) & 1u);   // RNE
    return (bf16_t)(u >> 16);
}
static __device__ __forceinline__ float bf_lo(u32 u) { return __uint_as_float(u << 16); }
static __device__ __forceinline__ float bf_hi(u32 u) { return __uint_as_float(u & 0xFFFF0000u); }
static __device__ __forceinline__ u32 pack2(float a, float b) {
    return (u32)f2bf(a) | ((u32)f2bf(b) << 16);
}

// ---------- repack weights ----------
// dec_w [co][ci][3][3] -> wB bf16, 32x32x16 B-frag order:
//   frag=(r*4+kc)*2+q ; wB[(frag*64+l)*8+j] = w[co=q*32+(l&31)][ci=kc*16+((l>>5)&1)*8+j][r]
// enc_w [co][3][3][3] (= [co][k], k=ci*9+tap, 27) -> wEB bf16, K padded to 32 with ZEROS:
//   frag=s*2+n ; wEB[(frag*64+l)*8+j] = k<27 ? w[co=n*32+(l&31)][k=s*16+((l>>5)&1)*8+j] : 0
__global__ void repack_w(const float* __restrict__ dec_w, const float* __restrict__ enc_w,
                         bf16_t* __restrict__ wB, bf16_t* __restrict__ wEB) {
    int i = blockIdx.x * 256 + threadIdx.x;
    if (i < 36864) {
        int j  = i & 7;
        int l  = (i >> 3) & 63;
        int q  = (i >> 9) & 1;
        int kc = (i >> 10) & 3;
        int r  = i >> 12;
        int co = q * 32 + (l & 31);
        int ci = kc * 16 + ((l >> 5) & 1) * 8 + j;
        wB[i] = f2bf(dec_w[(co * 64 + ci) * 9 + r]);
    } else if (i < 36864 + 2048) {
        int t = i - 36864;
        int j = t & 7;
        int l = (t >> 3) & 63;
        int n = (t >> 9) & 1;
        int s = (t >> 10) & 1;
        int co = n * 32 + (l & 31);
        int k  = s * 16 + ((l >> 5) & 1) * 8 + j;
        wEB[t] = (k < 27) ? f2bf(enc_w[co * 27 + k]) : (bf16_t)0;
    }
}

// ---------- zero the 1-px halo of a padded NHWC [nimg][258][258][64] bf16 buffer ----------
__global__ void zero_halo(bf16_t* __restrict__ buf, int nimg) {
    const int per_img = 1028 * 8;   // border pixels * 8 chunks of 16B
    int i = blockIdx.x * 256 + threadIdx.x;
    if (i >= nimg * per_img) return;
    int z = i / per_img;
    int rem = i - z * per_img;
    int p = rem >> 3, q = rem & 7;
    int row, col;
    if (p < 258)      { row = 0;           col = p; }
    else if (p < 516) { row = 257;         col = p - 258; }
    else if (p < 772) { row = p - 516 + 1; col = 0; }
    else              { row = p - 772 + 1; col = 257; }
    *(uint4*)(buf + ((size_t)z * HP * WP + (size_t)row * WP + col) * 64 + q * 8) =
        make_uint4(0u, 0u, 0u, 0u);
}

// ---------- encoder (MFMA im2col): x f32 -> f[z][258][258][64] bf16 ----------
// 512 thr = 8 waves; 16x16 output px tile, all 64 co. GEMM: M=256 px, N=64, K=27->32.
// Wave w owns M-frag w (tile rows 2w,2w+1). A gathered per-lane from bf16 x-tile in LDS.
// B zero-padded for k>=27, so clamped-A garbage contributes nothing.
__global__ __launch_bounds__(512) void encoder_mfma(
    const float* __restrict__ x, const bf16_t* __restrict__ wEB,
    const float* __restrict__ enc_b, bf16_t* __restrict__ f, int b0)
{
    __shared__ __align__(16) bf16_t xt[3][33][34];   // 6,732 B
    __shared__ __align__(16) bf16_t ot[256 * 72];    // 36,864 B

    const int tid = threadIdx.x;
    const int w   = tid >> 6;
    const int l   = tid & 63;
    const int z   = blockIdx.z;
    const int b   = b0 + z;
    const int Y0  = blockIdx.y << 5;   // input-row base (stride 2)
    const int X0  = blockIdx.x << 5;

    const int col = l & 31;
    const float bias0 = enc_b[col];
    const float bias1 = enc_b[32 + col];

    // B fragments (tiny, L2-hot)
    const bf16x8* wv = (const bf16x8*)wEB;
    bf16x8 Bf[2][2];
    #pragma unroll
    for (int s = 0; s < 2; ++s) {
        Bf[s][0] = wv[((s * 2 + 0) << 6) + l];
        Bf[s][1] = wv[((s * 2 + 1) << 6) + l];
    }

    // ---- stage 33x33x3 x-tile as bf16 ----
    const float* xb = x + (size_t)b * 3 * HIN * WIN;
    for (int i = tid; i < 3267; i += 512) {
        int ci  = i / 1089;
        int rem = i - ci * 1089;
        int yy  = rem / 33, xx = rem - yy * 33;
        int iy = Y0 + yy, ix = X0 + xx;
        float v = (iy < HIN && ix < WIN)
                ? xb[(size_t)ci * HIN * WIN + (size_t)iy * WIN + ix] : 0.f;
        xt[ci][yy][xx] = f2bf(v);
    }
    __syncthreads();

    // ---- gather A fragments: row=l&31 -> (py,px); k=(l>>5)*8+j (+16 for kstep 1) ----
    const int row = l & 31;
    const int py  = 2 * w + (row >> 4);   // tile row 0..15
    const int px  = row & 15;
    const int kh  = (l >> 5) * 8;
    bf16x8 A[2];
    #pragma unroll
    for (int s = 0; s < 2; ++s) {
        #pragma unroll
        for (int j = 0; j < 8; ++j) {
            int k = s * 16 + kh + j;
            k = k < 27 ? k : 26;              // clamp; B=0 kills k>=27
            int ci  = (k * 29) >> 8;          // k/9 for k<27
            int tap = k - ci * 9;
            int dy  = (tap * 11) >> 5;        // tap/3 for tap<9
            int dx  = tap - dy * 3;
            A[s][j] = (short)xt[ci][2 * py + dy][2 * px + dx];
        }
    }

    f32x16 acc[2];
    acc[0] = (f32x16){0.f,0.f,0.f,0.f,0.f,0.f,0.f,0.f,0.f,0.f,0.f,0.f,0.f,0.f,0.f,0.f};
    acc[1] = acc[0];
    acc[0] = __builtin_amdgcn_mfma_f32_32x32x16_bf16(A[0], Bf[0][0], acc[0], 0, 0, 0);
    acc[1] = __builtin_amdgcn_mfma_f32_32x32x16_bf16(A[0], Bf[0][1], acc[1], 0, 0, 0);
    acc[0] = __builtin_amdgcn_mfma_f32_32x32x16_bf16(A[1], Bf[1][0], acc[0], 0, 0, 0);
    acc[1] = __builtin_amdgcn_mfma_f32_32x32x16_bf16(A[1], Bf[1][1], acc[1], 0, 0, 0);

    // ---- epilogue: bias+relu -> LDS [256 px][stride 72] -> contiguous stores ----
    #pragma unroll
    for (int q = 0; q < 2; ++q) {
        const float bs = q ? bias1 : bias0;
        #pragma unroll
        for (int v = 0; v < 16; ++v) {
            const int grow = (v & 3) + 8 * (v >> 2) + 4 * (l >> 5);
            const int flat = w * 32 + grow;
            float t = acc[q][v] + bs;
            t = t > 0.f ? t : 0.f;
            ot[flat * 72 + q * 32 + col] = f2bf(t);
        }
    }
    __syncthreads();

    bf16_t* fz = f + (size_t)z * HP * WP * 64;
    const int by = blockIdx.y << 4, bx = blockIdx.x << 4;
    #pragma unroll
    for (int it = 0; it < 16; ++it) {
        int i = it * 512 + tid;
        int p = i >> 5, c = i & 31;
        u32 v = *(const u32*)(ot + p * 72 + c * 2);
        int pyy = p >> 4, pxx = p & 15;
        *((u32*)(fz + ((size_t)(by + pyy + 1) * WP + (bx + pxx + 1)) * 64) + c) = v;
    }
}

// ---------- decoder (MFMA 32x32x16): 512 thr = 8 waves, 16x16 tile ----------
__global__ __launch_bounds__(512, 4) void decoder_mfma(
    const bf16_t* __restrict__ f, const bf16_t* __restrict__ wB,
    const float* __restrict__ dec_b, bf16_t* __restrict__ d)
{
    __shared__ __align__(16) bf16_t tile[18 * 18 * 64];   // 41,472 B; epilogue reuses as [256][72]

    const int tid = threadIdx.x;
    const int w   = tid >> 6;          // 0..7
    const int l   = tid & 63;
    const int z   = blockIdx.z;
    const int y0  = blockIdx.y << 4, x0 = blockIdx.x << 4;

    const int col = l & 31;
    const float bias0 = dec_b[col];
    const float bias1 = dec_b[32 + col];

    const bf16_t* fbase = f + ((size_t)z * HP * WP + (size_t)y0 * WP + x0) * 64;
    for (int i = tid; i < 2592; i += 512) {
        int p   = i >> 3, qq = i & 7;
        int yy  = p / 18, xx = p - yy * 18;
        uint4 v = *(const uint4*)(fbase + ((size_t)yy * WP + xx) * 64 + qq * 8);
        int byteoff = (p * 128 + qq * 16) ^ ((p & 7) << 4);
        *(uint4*)((char*)tile + byteoff) = v;
    }

    f32x16 acc[2];
    acc[0] = (f32x16){0.f,0.f,0.f,0.f,0.f,0.f,0.f,0.f,0.f,0.f,0.f,0.f,0.f,0.f,0.f,0.f};
    acc[1] = acc[0];

    __syncthreads();

    const bf16x8* wBv = (const bf16x8*)wB;
    const int ty_l = (l >> 4) & 1;
    const int tx_l = l & 15;
    const int kh16 = (l >> 5) << 4;

    #pragma unroll
    for (int r = 0; r < 9; ++r) {
        const int dy = r / 3, dx = r - 3 * (r / 3);
        bf16x8 Bf[4][2];
        #pragma unroll
        for (int kc = 0; kc < 4; ++kc) {
            Bf[kc][0] = wBv[(((r * 4 + kc) << 1) + 0) * 64 + l];
            Bf[kc][1] = wBv[(((r * 4 + kc) << 1) + 1) * 64 + l];
        }
        const int p   = (2 * w + ty_l + dy) * 18 + tx_l + dx;
        const int swz = (p & 7) << 4;
        const int pb  = p * 128 + kh16;
        #pragma unroll
        for (int kc = 0; kc < 4; ++kc) {
            bf16x8 a = *(const bf16x8*)((const char*)tile + ((pb + kc * 32) ^ swz));
            acc[0] = __builtin_amdgcn_mfma_f32_32x32x16_bf16(a, Bf[kc][0], acc[0], 0, 0, 0);
            acc[1] = __builtin_amdgcn_mfma_f32_32x32x16_bf16(a, Bf[kc][1], acc[1], 0, 0, 0);
        }
    }

    __syncthreads();
    bf16_t* ot = tile;
    #pragma unroll
    for (int q = 0; q < 2; ++q) {
        const float bs = q ? bias1 : bias0;
        #pragma unroll
        for (int v = 0; v < 16; ++v) {
            const int grow = (v & 3) + 8 * (v >> 2) + 4 * (l >> 5);
            const int flat = w * 32 + grow;
            float t = acc[q][v] + bs;
            t = t > 0.f ? t : 0.f;
            ot[flat * 72 + q * 32 + col] = f2bf(t);
        }
    }
    __syncthreads();

    bf16_t* dz = d + (size_t)z * HP * WP * 64;
    #pragma unroll
    for (int it = 0; it < 16; ++it) {
        int i = it * 512 + tid;
        int p = i >> 5, c = i & 31;
        u32 v = *(const u32*)(ot + p * 72 + c * 2);
        int py = p >> 4, pxx = p & 15;
        *((u32*)(dz + ((size_t)(y0 + py + 1) * WP + (x0 + pxx + 1)) * 64) + c) = v;
    }
}

// ---------- head: d padded NHWC -> out f32, per-sample routed 3x3 conv 64->1 + bias ----------
__global__ __launch_bounds__(256) void head_kernel(
    const bf16_t* __restrict__ d, const float* __restrict__ head_w,
    const float* __restrict__ head_b, const int* __restrict__ cls_id,
    float* __restrict__ out, int b0)
{
    __shared__ __align__(16) bf16_t tile[18 * 18 * 64];
    __shared__ float hw[9][64];

    const int tid = threadIdx.x;
    const int z   = blockIdx.z;
    const int b   = b0 + z;
    const int y0  = blockIdx.y << 4, x0 = blockIdx.x << 4;
    const int cls = cls_id[b];

    for (int i = tid; i < 576; i += 256) {
        int r = i >> 6, ci = i & 63;
        hw[r][ci] = head_w[((size_t)cls * 64 + ci) * 9 + r];
    }
    const bf16_t* dbase = d + ((size_t)z * HP * WP + (size_t)y0 * WP + x0) * 64;
    for (int i = tid; i < 2592; i += 256) {
        int yy  = i / 144;
        int rem = i - yy * 144;
        int xx  = rem >> 3, q = rem & 7;
        int p   = yy * 18 + xx;
        uint4 v = *(const uint4*)(dbase + ((size_t)yy * WP + xx) * 64 + q * 8);
        int byteoff = (p * 128 + q * 16) ^ ((p & 7) << 4);
        *(uint4*)((char*)tile + byteoff) = v;
    }
    __syncthreads();

    const int py = tid >> 4, px = tid & 15;
    float a0 = 0.f, a1 = 0.f, a2 = 0.f, a3 = 0.f;
    #pragma unroll 1
    for (int r = 0; r < 9; ++r) {
        const int dy = r / 3, dx = r - 3 * (r / 3);
        const int p  = (py + dy) * 18 + px + dx;
        const int swz = (p & 7) << 4;
        const float* wr = &hw[r][0];
        #pragma unroll
        for (int q = 0; q < 8; ++q) {
            uint4 v = *(const uint4*)((const char*)tile + ((p * 128 + q * 16) ^ swz));
            float4 w0 = *(const float4*)(wr + q * 8);
            float4 w1 = *(const float4*)(wr + q * 8 + 4);
            float t0 = fmaf(bf_lo(v.x), w0.x, fmaf(bf_hi(v.x), w0.y, 0.f));
            float t1 = fmaf(bf_lo(v.y), w0.z, fmaf(bf_hi(v.y), w0.w, 0.f));
            float t2 = fmaf(bf_lo(v.z), w1.x, fmaf(bf_hi(v.z), w1.y, 0.f));
            float t3 = fmaf(bf_lo(v.w), w1.z, fmaf(bf_hi(v.w), w1.w, 0.f));
            a0 += t0; a1 += t1; a2 += t2; a3 += t3;
        }
    }
    const float acc = head_b[cls] + (a0 + a1) + (a2 + a3);
    out[(size_t)b * (HO * WO) + (size_t)(y0 + py) * WO + (x0 + px)] = acc;
}

extern "C" void kernel_launch(void* const* d_in, const int* in_sizes, int n_in,
                              void* d_out, int out_size, void* d_ws, size_t ws_size,
                              hipStream_t stream) {
    const float* x      = (const float*)d_in[0];
    const int*   cls_id = (const int*)  d_in[1];
    const float* enc_w  = (const float*)d_in[2];
    const float* enc_b  = (const float*)d_in[3];
    const float* dec_w  = (const float*)d_in[4];
    const float* dec_b  = (const float*)d_in[5];
    const float* head_w = (const float*)d_in[6];
    const float* head_b = (const float*)d_in[7];
    float* out = (float*)d_out;

    const size_t WB_RESERVE = 131072;
    const size_t PER_IMG    = (size_t)HP * WP * 64 * 2;   // 8,519,424 B
    char* ws = (char*)d_ws;
    bf16_t* wB  = (bf16_t*)ws;                 // 73,728 B
    bf16_t* wEB = (bf16_t*)(ws + 81920);       // 4,096 B

    size_t avail = (ws_size > WB_RESERVE) ? (ws_size - WB_RESERVE) : 0;
    int C = (int)(avail / (2 * PER_IMG));
    if (C < 1) C = 1;
    if (C > NIMG) C = NIMG;

    bf16_t* fbuf = (bf16_t*)(ws + WB_RESERVE);
    bf16_t* dbuf = (bf16_t*)(ws + WB_RESERVE + (size_t)C * PER_IMG);

    repack_w<<<dim3(152), 256, 0, stream>>>(dec_w, enc_w, wB, wEB);
    {
        int nthr = C * 1028 * 8;
        int nblk = (nthr + 255) / 256;
        zero_halo<<<dim3(nblk), 256, 0, stream>>>(fbuf, C);
        zero_halo<<<dim3(nblk), 256, 0, stream>>>(dbuf, C);
    }

    int n_rounds = (NIMG + C - 1) / C;
    int per = (NIMG + n_rounds - 1) / n_rounds;
    for (int b0 = 0; b0 < NIMG; b0 += per) {
        const int n = (NIMG - b0 < per) ? (NIMG - b0) : per;
        encoder_mfma<<<dim3(16, 16, n), 512, 0, stream>>>(x, wEB, enc_b, fbuf, b0);
        decoder_mfma<<<dim3(16, 16, n), 512, 0, stream>>>(fbuf, wB, dec_b, dbuf);
        head_kernel <<<dim3(16, 16, n), 256, 0, stream>>>(dbuf, head_w, head_b, cls_id, out, b0);
    }
}